// Round 8
// baseline (816.190 us; speedup 1.0000x reference)
//
#include <hip/hip_runtime.h>
#include <hip/hip_bf16.h>
#include <stdint.h>

// ---------- types / helpers ----------
typedef unsigned short u16;
using bf16x8 = __attribute__((ext_vector_type(8))) short;
using f32x4  = __attribute__((ext_vector_type(4))) float;
typedef unsigned short u16x4 __attribute__((ext_vector_type(4)));

#define AS1 __attribute__((address_space(1)))
#define AS3 __attribute__((address_space(3)))

__device__ __forceinline__ float bf2f(u16 x) {
    union { unsigned int u; float f; } v; v.u = ((unsigned int)x) << 16; return v.f;
}
__device__ __forceinline__ u16 f2bf(float f) {
    union { float f; unsigned int u; } v; v.f = f;
    return (u16)((v.u + 0x7fffu + ((v.u >> 16) & 1u)) >> 16);  // RNE
}

#define ACT_NONE 0
#define ACT_SOFTPLUS 1

// ---------- generic bf16 GEMM: C[M,N] = A[M,K] * B[N,K]^T ----------
// 128x128 tile, BK=64, 256 threads (4 waves 2x2), 16x16x32 bf16 MFMA.
// T3-min 2-phase: double-buffered LDS, stage(t+1) issued BEFORE compute(t),
// ONE barrier per K-step (its vmcnt0+lgkm0 drain lands after a compute phase
// of latency hiding). Race-free: stage writes buf[cur^1], reads buf[cur].
// kSlices>1: split-K over blockIdx.z with fp32 atomicAdd into pre-zeroed Cf.
// addC!=null (backward out_proj): epilogue computes final blend
//   out = (v + addC) * mask + hidden * (1-mask).
__global__ __launch_bounds__(256) void gemm_bt_kernel(
    const u16* __restrict__ A, int lda,
    const u16* __restrict__ B,              // ldb == K
    float* __restrict__ Cf, u16* __restrict__ Cb,
    const float* __restrict__ bias,
    int ldc, int M, int N, int K, int Nreal,
    int flipA, int flipC, int act, int kSlices,
    const float* __restrict__ addC, const float* __restrict__ hid,
    const float* __restrict__ msk)
{
    __shared__ __align__(16) u16 As[2][128 * 64];
    __shared__ __align__(16) u16 Bs[2][128 * 64];

    const int tid  = threadIdx.x;
    const int bm   = blockIdx.y * 128;
    const int bn   = blockIdx.x * 128;
    const int lane = tid & 63;
    const int wid  = tid >> 6;
    const int wr   = (wid >> 1) * 64;
    const int wc   = (wid & 1) * 64;
    const int l15  = lane & 15;
    const int l4   = lane >> 4;

    const int kLen = K / kSlices;
    const int kt0  = (blockIdx.z * kLen) >> 6;   // first global k-tile
    const int nK   = kLen >> 6;

    f32x4 acc[4][4];
    const f32x4 vzero = {0.f, 0.f, 0.f, 0.f};
    #pragma unroll
    for (int i = 0; i < 4; ++i)
        #pragma unroll
        for (int j = 0; j < 4; ++j) acc[i][j] = vzero;

    auto stage = [&](int buf, int kt) {
        #pragma unroll
        for (int i = 0; i < 4; ++i) {
            int off  = i * 4096 + tid * 16;     // byte offset in half-tile
            int row  = off >> 7;
            int colB = off & 127;
            int rowG = bm + row;
            if (flipA) { int b = rowG >> 11; int l = rowG & 2047; rowG = (b << 11) + (2047 - l); }
            const char* src = (const char*)A + ((size_t)rowG * lda + ((size_t)kt << 6)) * 2 + colB;
            __builtin_amdgcn_global_load_lds((const AS1 unsigned int*)src,
                                             (AS3 unsigned int*)((char*)As[buf] + off), 16, 0, 0);
        }
        #pragma unroll
        for (int i = 0; i < 4; ++i) {
            int off  = i * 4096 + tid * 16;
            int row  = off >> 7;
            int colB = off & 127;
            int rowG = bn + row;
            const char* src = (const char*)B + ((size_t)rowG * K + ((size_t)kt << 6)) * 2 + colB;
            __builtin_amdgcn_global_load_lds((const AS1 unsigned int*)src,
                                             (AS3 unsigned int*)((char*)Bs[buf] + off), 16, 0, 0);
        }
    };

    stage(0, kt0);
    __syncthreads();                        // drain prologue loads

    int cur = 0;
    for (int t = 0; t < nK; ++t) {
        if (t + 1 < nK) stage(cur ^ 1, kt0 + t + 1);   // overlap with compute

        #pragma unroll
        for (int kk = 0; kk < 2; ++kk) {
            bf16x8 af[4], bfr[4];
            #pragma unroll
            for (int mt = 0; mt < 4; ++mt) {
                int row = wr + mt * 16 + l15;
                af[mt] = *(const bf16x8*)((const char*)As[cur] + row * 128 + kk * 64 + l4 * 16);
            }
            #pragma unroll
            for (int nt = 0; nt < 4; ++nt) {
                int row = wc + nt * 16 + l15;
                bfr[nt] = *(const bf16x8*)((const char*)Bs[cur] + row * 128 + kk * 64 + l4 * 16);
            }
            #pragma unroll
            for (int mt = 0; mt < 4; ++mt)
                #pragma unroll
                for (int nt = 0; nt < 4; ++nt)
                    acc[mt][nt] = __builtin_amdgcn_mfma_f32_16x16x32_bf16(
                        af[mt], bfr[nt], acc[mt][nt], 0, 0, 0);
        }
        __syncthreads();                    // next tile landed; reads done
        cur ^= 1;
    }

    // epilogue: D[row][col]: col = lane&15, row = (lane>>4)*4 + r  (m89-verified)
    #pragma unroll
    for (int mt = 0; mt < 4; ++mt) {
        #pragma unroll
        for (int nt = 0; nt < 4; ++nt) {
            int col = bn + wc + nt * 16 + l15;
            if (col >= Nreal) continue;
            #pragma unroll
            for (int r = 0; r < 4; ++r) {
                int rowG = bm + wr + mt * 16 + l4 * 4 + r;
                float v = acc[mt][nt][r];
                if (act == ACT_SOFTPLUS) {
                    v += bias[col];
                    v = fmaxf(v, 0.f) + log1pf(__expf(-fabsf(v)));
                }
                int rw = rowG;
                if (flipC) { int b = rw >> 11; int l = rw & 2047; rw = (b << 11) + (2047 - l); }
                size_t ci = (size_t)rw * ldc + col;
                if (kSlices > 1) {
                    atomicAdd(&Cf[ci], v);
                } else if (addC) {
                    float m = msk[rw];
                    float tot = v + addC[ci];
                    Cf[ci] = tot * m + hid[ci] * (1.f - m);
                } else if (Cb) {
                    Cb[ci] = f2bf(v);
                } else {
                    Cf[ci] = v;
                }
            }
        }
    }
}

// ---------- causal depthwise conv (w=4) + silu, sliding-window ----------
__global__ void conv_silu_kernel(const u16* __restrict__ xz,
                                 const float* __restrict__ cw,
                                 const float* __restrict__ cb,
                                 u16* __restrict__ u)
{
    int d  = blockIdx.x * 256 + threadIdx.x;
    int r0 = blockIdx.y * 16;
    float w0 = cw[d*4+0], w1 = cw[d*4+1], w2 = cw[d*4+2], w3 = cw[d*4+3];
    float bias = cb[d];
    float x1, x2, x3;
    if (r0 & 2047) {
        x1 = bf2f(xz[(size_t)(r0-1) * 4096 + d]);
        x2 = bf2f(xz[(size_t)(r0-2) * 4096 + d]);
        x3 = bf2f(xz[(size_t)(r0-3) * 4096 + d]);
    } else { x1 = x2 = x3 = 0.f; }
    #pragma unroll
    for (int i = 0; i < 16; ++i) {
        int r = r0 + i;
        float x0 = bf2f(xz[(size_t)r * 4096 + d]);
        float acc = fmaf(w3, x0, fmaf(w2, x1, fmaf(w1, x2, fmaf(w0, x3, bias))));
        float sig = 1.f / (1.f + __expf(-acc));
        u[(size_t)r * 2048 + d] = f2bf(acc * sig);
        x3 = x2; x2 = x1; x1 = x0;
    }
}

// ---------- chunked selective scan, register-state layout (unchanged) ----------
#define NCH 32
#define CSZ 64
#define SUB 16
#define LW  264

__global__ __launch_bounds__(256) void scan_part1(
    const u16* __restrict__ delta, const u16* __restrict__ u,
    const float* __restrict__ dbc, const float* __restrict__ A_log,
    float* __restrict__ P, float* __restrict__ S)
{
    __shared__ __align__(16) u16   dl_s[SUB * LW];
    __shared__ __align__(16) u16   ul_s[SUB * LW];
    __shared__ __align__(16) float b_s[SUB * 16];

    const int tid = threadIdx.x;
    const int d0  = blockIdx.x * 256;
    const int c   = blockIdx.y;
    const int b   = blockIdx.z;
    const int d   = d0 + tid;
    const size_t rbase = (size_t)b * 2048 + c * CSZ;

    float a2[16], h[16], p[16];
    #pragma unroll
    for (int q = 0; q < 4; ++q) {
        float4 al = *(const float4*)&A_log[(size_t)d * 16 + q * 4];
        a2[q*4+0] = -__expf(al.x) * 1.4426950408889634f;
        a2[q*4+1] = -__expf(al.y) * 1.4426950408889634f;
        a2[q*4+2] = -__expf(al.z) * 1.4426950408889634f;
        a2[q*4+3] = -__expf(al.w) * 1.4426950408889634f;
    }
    #pragma unroll
    for (int n = 0; n < 16; ++n) { h[n] = 0.f; p[n] = 1.f; }

    const int sr  = tid >> 4;
    const int sc16 = (tid & 15) * 16;

    for (int sch = 0; sch < CSZ / SUB; ++sch) {
        {
            size_t row = rbase + sch * SUB + sr;
            *(bf16x8*)&dl_s[sr * LW + sc16]     = *(const bf16x8*)&delta[row * 2048 + d0 + sc16];
            *(bf16x8*)&dl_s[sr * LW + sc16 + 8] = *(const bf16x8*)&delta[row * 2048 + d0 + sc16 + 8];
            *(bf16x8*)&ul_s[sr * LW + sc16]     = *(const bf16x8*)&u[row * 2048 + d0 + sc16];
            *(bf16x8*)&ul_s[sr * LW + sc16 + 8] = *(const bf16x8*)&u[row * 2048 + d0 + sc16 + 8];
            if (tid < 64) {
                int r2 = tid >> 2, c4 = (tid & 3) * 4;
                size_t g2 = rbase + sch * SUB + r2;
                *(float4*)&b_s[r2 * 16 + c4] = *(const float4*)&dbc[g2 * 96 + 64 + c4];
            }
        }
        __syncthreads();
        for (int s = 0; s < SUB; ++s) {
            float dv  = bf2f(dl_s[s * LW + tid]);
            float uv  = bf2f(ul_s[s * LW + tid]);
            float dvu = dv * uv;
            const float4* Bp = (const float4*)&b_s[s * 16];
            #pragma unroll
            for (int q = 0; q < 4; ++q) {
                float4 Bq = Bp[q];
                #pragma unroll
                for (int j = 0; j < 4; ++j) {
                    int n = q * 4 + j;
                    float dA = exp2f(dv * a2[n]);
                    h[n] = fmaf(dA, h[n], dvu * ((&Bq.x)[j]));
                    p[n] *= dA;
                }
            }
        }
        __syncthreads();
    }

    size_t base = (((size_t)(b * NCH + c)) << 15) + (size_t)d * 16;
    #pragma unroll
    for (int q = 0; q < 4; ++q) {
        float4 pv = { p[q*4+0], p[q*4+1], p[q*4+2], p[q*4+3] };
        float4 sv = { h[q*4+0], h[q*4+1], h[q*4+2], h[q*4+3] };
        *(float4*)&P[base + q * 4] = pv;
        *(float4*)&S[base + q * 4] = sv;
    }
}

__global__ void scan_part2(const float* __restrict__ P, float* __restrict__ S)
{
    int i  = blockIdx.x * 256 + threadIdx.x;
    int b  = i >> 15;
    int dn = i & 32767;
    size_t base = ((size_t)b * NCH) << 15;
    float h = 0.f;
    #pragma unroll 4
    for (int c = 0; c < NCH; ++c) {
        size_t idx = base + ((size_t)c << 15) + dn;
        float p = P[idx];
        float s = S[idx];
        S[idx] = h;
        h = fmaf(p, h, s);
    }
}

__global__ __launch_bounds__(256) void scan_part3(
    const u16* __restrict__ delta, const u16* __restrict__ u,
    const float* __restrict__ dbc, const u16* __restrict__ xz,
    const float* __restrict__ A_log, const float* __restrict__ Dp,
    const float* __restrict__ Hin, u16* __restrict__ y)
{
    __shared__ __align__(16) u16   dl_s[SUB * LW];
    __shared__ __align__(16) u16   ul_s[SUB * LW];
    __shared__ __align__(16) u16   zl_s[SUB * LW];
    __shared__ __align__(16) float bc_s[SUB * 32];

    const int tid = threadIdx.x;
    const int d0  = blockIdx.x * 256;
    const int c   = blockIdx.y;
    const int b   = blockIdx.z;
    const int d   = d0 + tid;
    const size_t rbase = (size_t)b * 2048 + c * CSZ;

    float a2[16], h[16];
    #pragma unroll
    for (int q = 0; q < 4; ++q) {
        float4 al = *(const float4*)&A_log[(size_t)d * 16 + q * 4];
        a2[q*4+0] = -__expf(al.x) * 1.4426950408889634f;
        a2[q*4+1] = -__expf(al.y) * 1.4426950408889634f;
        a2[q*4+2] = -__expf(al.z) * 1.4426950408889634f;
        a2[q*4+3] = -__expf(al.w) * 1.4426950408889634f;
    }
    {
        size_t base = (((size_t)(b * NCH + c)) << 15) + (size_t)d * 16;
        #pragma unroll
        for (int q = 0; q < 4; ++q) {
            float4 hv = *(const float4*)&Hin[base + q * 4];
            h[q*4+0] = hv.x; h[q*4+1] = hv.y; h[q*4+2] = hv.z; h[q*4+3] = hv.w;
        }
    }
    const float Dd = Dp[d];

    const int sr   = tid >> 4;
    const int sc16 = (tid & 15) * 16;

    for (int sch = 0; sch < CSZ / SUB; ++sch) {
        {
            size_t row = rbase + sch * SUB + sr;
            *(bf16x8*)&dl_s[sr * LW + sc16]     = *(const bf16x8*)&delta[row * 2048 + d0 + sc16];
            *(bf16x8*)&dl_s[sr * LW + sc16 + 8] = *(const bf16x8*)&delta[row * 2048 + d0 + sc16 + 8];
            *(bf16x8*)&ul_s[sr * LW + sc16]     = *(const bf16x8*)&u[row * 2048 + d0 + sc16];
            *(bf16x8*)&ul_s[sr * LW + sc16 + 8] = *(const bf16x8*)&u[row * 2048 + d0 + sc16 + 8];
            *(bf16x8*)&zl_s[sr * LW + sc16]     = *(const bf16x8*)&xz[row * 4096 + 2048 + d0 + sc16];
            *(bf16x8*)&zl_s[sr * LW + sc16 + 8] = *(const bf16x8*)&xz[row * 4096 + 2048 + d0 + sc16 + 8];
            if (tid < 128) {
                int r2 = tid >> 3, c4 = (tid & 7) * 4;
                size_t g2 = rbase + sch * SUB + r2;
                *(float4*)&bc_s[r2 * 32 + c4] = *(const float4*)&dbc[g2 * 96 + 64 + c4];
            }
        }
        __syncthreads();
        for (int s = 0; s < SUB; ++s) {
            float dv  = bf2f(dl_s[s * LW + tid]);
            float uv  = bf2f(ul_s[s * LW + tid]);
            float dvu = dv * uv;
            float yv  = 0.f;
            const float4* Bp = (const float4*)&bc_s[s * 32];
            const float4* Cp = (const float4*)&bc_s[s * 32 + 16];
            #pragma unroll
            for (int q = 0; q < 4; ++q) {
                float4 Bq = Bp[q];
                float4 Cq = Cp[q];
                #pragma unroll
                for (int j = 0; j < 4; ++j) {
                    int n = q * 4 + j;
                    float dA = exp2f(dv * a2[n]);
                    h[n] = fmaf(dA, h[n], dvu * ((&Bq.x)[j]));
                    yv   = fmaf(h[n], ((&Cq.x)[j]), yv);
                }
            }
            float zv  = bf2f(zl_s[s * LW + tid]);
            float sig = 1.f / (1.f + __expf(-zv));
            float out = (yv + uv * Dd) * (zv * sig);
            y[(rbase + sch * SUB + s) * 2048 + d] = f2bf(out);
        }
        __syncthreads();
    }
}

// ---------- elementwise ----------
__global__ void blend_kernel(const float* __restrict__ hidden, const float* __restrict__ mask,
                             const float* __restrict__ mw, const float* __restrict__ mb,
                             u16* __restrict__ xm)
{
    size_t i = (size_t)blockIdx.x * 256 + threadIdx.x;
    int r = (int)(i >> 10), c = (int)(i & 1023);
    float m = mask[r];
    float v = hidden[i] * m + (m * mw[c] + mb[c]) * (1.f - m);
    xm[i] = f2bf(v);
}

// ---------- fused weight conversion (all 8 weights, both dirs) ----------
struct CvtArgs { const float* src[8]; u16* dst[8]; };
// segs: 0,1 = w_in (4194304 ea); 2,3 = w_out (2097152 ea); 4,5 = w_dt (131072 ea);
// 6,7 = w_xp padded 96->128 rows x 2048 (262144 ea, zero pad)
__global__ void cvt_weights_kernel(CvtArgs a)
{
    size_t i = (size_t)blockIdx.x * 256 + threadIdx.x;   // < 13369344
    if (i < 8388608) {
        int s = (int)(i >> 22);            // 0 or 1
        size_t j = i & 4194303;
        a.dst[s][j] = f2bf(a.src[s][j]);
    } else if (i < 12582912) {
        size_t k = i - 8388608;
        int s = 2 + (int)(k >> 21);
        size_t j = k & 2097151;
        a.dst[s][j] = f2bf(a.src[s][j]);
    } else if (i < 12845056) {
        size_t k = i - 12582912;
        int s = 4 + (int)(k >> 17);
        size_t j = k & 131071;
        a.dst[s][j] = f2bf(a.src[s][j]);
    } else if (i < 13369344) {
        size_t k = i - 12845056;
        int s = 6 + (int)(k >> 18);
        size_t j = k & 262143;
        int r = (int)(j >> 11), c = (int)(j & 2047);
        a.dst[s][j] = (r < 96) ? f2bf(a.src[s][(size_t)r * 2048 + c]) : (u16)0;
    }
}

__global__ void cvt_dt_kernel(const float* __restrict__ dbc, u16* __restrict__ dst) {
    int i = blockIdx.x * 256 + threadIdx.x;   // 4096*64
    int r = i >> 6, c = i & 63;
    dst[i] = f2bf(dbc[(size_t)r * 96 + c]);
}

// ---------- launcher ----------
extern "C" void kernel_launch(void* const* d_in, const int* in_sizes, int n_in,
                              void* d_out, int out_size, void* d_ws, size_t ws_size,
                              hipStream_t stream)
{
    (void)in_sizes; (void)n_in; (void)out_size; (void)ws_size;
    const float* hidden = (const float*)d_in[0];
    const float* mask   = (const float*)d_in[1];
    const float* mpw    = (const float*)d_in[2];
    const float* mpb    = (const float*)d_in[3];

    char* ws = (char*)d_ws;
    size_t off = 0;
    auto alloc = [&](size_t bytes) -> char* {
        char* p = ws + off; off += (bytes + 255) & ~(size_t)255; return p;
    };
    u16*   xm    = (u16*)  alloc(4096ull * 1024 * 2);
    u16*   xz    = (u16*)  alloc(4096ull * 4096 * 2);
    u16*   ub    = (u16*)  alloc(4096ull * 2048 * 2);
    float* dbc   = (float*)alloc(4096ull * 96 * 4);
    u16*   dtb   = (u16*)  alloc(4096ull * 64 * 2);
    u16*   delta = (u16*)  alloc(4096ull * 2048 * 2);
    u16*   yb    = (u16*)  alloc(4096ull * 2048 * 2);
    float* fout  = (float*)alloc(4096ull * 1024 * 4);
    float* Pbuf  = (float*)alloc(2ull * NCH * 2048 * 16 * 4);
    float* Sbuf  = (float*)alloc(2ull * NCH * 2048 * 16 * 4);
    u16* w_in[2]  = { (u16*)alloc(4096ull*1024*2), (u16*)alloc(4096ull*1024*2) };
    u16* w_xp[2]  = { (u16*)alloc(128ull*2048*2),  (u16*)alloc(128ull*2048*2)  };
    u16* w_dt[2]  = { (u16*)alloc(2048ull*64*2),   (u16*)alloc(2048ull*64*2)   };
    u16* w_out[2] = { (u16*)alloc(1024ull*2048*2), (u16*)alloc(1024ull*2048*2) };

    // one fused weight-conversion dispatch
    {
        CvtArgs ca;
        ca.src[0] = (const float*)d_in[4];  ca.dst[0] = w_in[0];
        ca.src[1] = (const float*)d_in[13]; ca.dst[1] = w_in[1];
        ca.src[2] = (const float*)d_in[12]; ca.dst[2] = w_out[0];
        ca.src[3] = (const float*)d_in[21]; ca.dst[3] = w_out[1];
        ca.src[4] = (const float*)d_in[8];  ca.dst[4] = w_dt[0];
        ca.src[5] = (const float*)d_in[17]; ca.dst[5] = w_dt[1];
        ca.src[6] = (const float*)d_in[7];  ca.dst[6] = w_xp[0];
        ca.src[7] = (const float*)d_in[16]; ca.dst[7] = w_xp[1];
        cvt_weights_kernel<<<(13369344 + 255) / 256, 256, 0, stream>>>(ca);
    }
    blend_kernel<<<16384, 256, 0, stream>>>(hidden, mask, mpw, mpb, xm);

    for (int dir = 0; dir < 2; ++dir) {
        int base = 4 + dir * 9;
        const float* conv_w = (const float*)d_in[base+1];
        const float* conv_b = (const float*)d_in[base+2];
        const float* dt_b   = (const float*)d_in[base+5];
        const float* A_log  = (const float*)d_in[base+6];
        const float* Dp     = (const float*)d_in[base+7];
        int flip = dir;

        // in_proj: xz = xm @ in_w^T  (A rows flipped for bwd)
        gemm_bt_kernel<<<dim3(32, 32, 1), 256, 0, stream>>>(
            xm, 1024, w_in[dir], nullptr, xz, nullptr, 4096, 4096, 4096, 1024, 4096,
            flip, 0, ACT_NONE, 1, nullptr, nullptr, nullptr);
        conv_silu_kernel<<<dim3(8, 256), 256, 0, stream>>>(xz, conv_w, conv_b, ub);
        // xproj split-K x4 with atomic accumulation into zeroed dbc
        hipMemsetAsync(dbc, 0, 4096ull * 96 * 4, stream);
        gemm_bt_kernel<<<dim3(1, 32, 4), 256, 0, stream>>>(
            ub, 2048, w_xp[dir], dbc, nullptr, nullptr, 96, 4096, 128, 2048, 96,
            0, 0, ACT_NONE, 4, nullptr, nullptr, nullptr);
        cvt_dt_kernel<<<(4096*64)/256, 256, 0, stream>>>(dbc, dtb);
        gemm_bt_kernel<<<dim3(16, 32, 1), 256, 0, stream>>>(
            dtb, 64, w_dt[dir], nullptr, delta, dt_b, 2048, 4096, 2048, 64, 2048,
            0, 0, ACT_SOFTPLUS, 1, nullptr, nullptr, nullptr);
        scan_part1<<<dim3(8, NCH, 2), 256, 0, stream>>>(delta, ub, dbc, A_log, Pbuf, Sbuf);
        scan_part2<<<256, 256, 0, stream>>>(Pbuf, Sbuf);
        scan_part3<<<dim3(8, NCH, 2), 256, 0, stream>>>(delta, ub, dbc, xz, A_log, Dp, Sbuf, yb);
        // out_proj; backward pass fuses the final mask-blend epilogue
        if (dir == 0) {
            gemm_bt_kernel<<<dim3(8, 32, 1), 256, 0, stream>>>(
                yb, 2048, w_out[0], fout, nullptr, nullptr, 1024, 4096, 1024, 2048, 1024,
                0, 0, ACT_NONE, 1, nullptr, nullptr, nullptr);
        } else {
            gemm_bt_kernel<<<dim3(8, 32, 1), 256, 0, stream>>>(
                yb, 2048, w_out[1], (float*)d_out, nullptr, nullptr, 1024, 4096, 1024, 2048, 1024,
                0, 1, ACT_NONE, 1, fout, hidden, mask);
        }
    }
}

// Round 9
// 763.078 us; speedup vs baseline: 1.0696x; 1.0696x over previous
//
#include <hip/hip_runtime.h>
#include <hip/hip_bf16.h>
#include <stdint.h>

// ---------- types / helpers ----------
typedef unsigned short u16;
using bf16x8 = __attribute__((ext_vector_type(8))) short;
using f32x4  = __attribute__((ext_vector_type(4))) float;
typedef unsigned short u16x4 __attribute__((ext_vector_type(4)));

#define AS1 __attribute__((address_space(1)))
#define AS3 __attribute__((address_space(3)))

__device__ __forceinline__ float bf2f(u16 x) {
    union { unsigned int u; float f; } v; v.u = ((unsigned int)x) << 16; return v.f;
}
__device__ __forceinline__ u16 f2bf(float f) {
    union { float f; unsigned int u; } v; v.f = f;
    return (u16)((v.u + 0x7fffu + ((v.u >> 16) & 1u)) >> 16);  // RNE
}

#define ACT_NONE 0
#define ACT_SOFTPLUS 1

// ---------- generic bf16 GEMM: C[M,N] = A[M,K] * B[N,K]^T ----------
// 128x128 tile, BK=64, 256 threads (4 waves 2x2), single-buffered LDS
// (round-7 proven; round-8 dbuf variant measured SLOWER — reverted).
// kSlices>1: split-K over blockIdx.z, fp32 atomicAdd into pre-zeroed Cf.
// hid!=null: fused final blend  out = v*msk[row] + hid[ci]*(1-msk[row]).
__global__ __launch_bounds__(256) void gemm_bt_kernel(
    const u16* __restrict__ A, int lda,
    const u16* __restrict__ B,              // ldb == K
    float* __restrict__ Cf, u16* __restrict__ Cb,
    const float* __restrict__ bias,
    int ldc, int M, int N, int K, int Nreal,
    int act, int kSlices,
    const float* __restrict__ hid, const float* __restrict__ msk)
{
    __shared__ __align__(16) u16 As[128 * 64];
    __shared__ __align__(16) u16 Bs[128 * 64];

    const int tid  = threadIdx.x;
    const int bm   = blockIdx.y * 128;
    const int bn   = blockIdx.x * 128;
    const int lane = tid & 63;
    const int wid  = tid >> 6;
    const int wr   = (wid >> 1) * 64;
    const int wc   = (wid & 1) * 64;
    const int l15  = lane & 15;
    const int l4   = lane >> 4;

    const int kLen = K / kSlices;
    const int kt0  = (blockIdx.z * kLen) >> 6;
    const int nK   = kLen >> 6;

    f32x4 acc[4][4];
    const f32x4 vzero = {0.f, 0.f, 0.f, 0.f};
    #pragma unroll
    for (int i = 0; i < 4; ++i)
        #pragma unroll
        for (int j = 0; j < 4; ++j) acc[i][j] = vzero;

    for (int t = 0; t < nK; ++t) {
        int kt = kt0 + t;
        #pragma unroll
        for (int i = 0; i < 4; ++i) {
            int off  = i * 4096 + tid * 16;
            int row  = off >> 7;
            int colB = off & 127;
            const char* src = (const char*)A + ((size_t)(bm + row) * lda + ((size_t)kt << 6)) * 2 + colB;
            __builtin_amdgcn_global_load_lds((const AS1 unsigned int*)src,
                                             (AS3 unsigned int*)((char*)As + off), 16, 0, 0);
        }
        #pragma unroll
        for (int i = 0; i < 4; ++i) {
            int off  = i * 4096 + tid * 16;
            int row  = off >> 7;
            int colB = off & 127;
            const char* src = (const char*)B + ((size_t)(bn + row) * K + ((size_t)kt << 6)) * 2 + colB;
            __builtin_amdgcn_global_load_lds((const AS1 unsigned int*)src,
                                             (AS3 unsigned int*)((char*)Bs + off), 16, 0, 0);
        }
        __syncthreads();

        #pragma unroll
        for (int kk = 0; kk < 2; ++kk) {
            bf16x8 af[4], bfr[4];
            #pragma unroll
            for (int mt = 0; mt < 4; ++mt) {
                int row = wr + mt * 16 + l15;
                af[mt] = *(const bf16x8*)((const char*)As + row * 128 + kk * 64 + l4 * 16);
            }
            #pragma unroll
            for (int nt = 0; nt < 4; ++nt) {
                int row = wc + nt * 16 + l15;
                bfr[nt] = *(const bf16x8*)((const char*)Bs + row * 128 + kk * 64 + l4 * 16);
            }
            #pragma unroll
            for (int mt = 0; mt < 4; ++mt)
                #pragma unroll
                for (int nt = 0; nt < 4; ++nt)
                    acc[mt][nt] = __builtin_amdgcn_mfma_f32_16x16x32_bf16(
                        af[mt], bfr[nt], acc[mt][nt], 0, 0, 0);
        }
        __syncthreads();
    }

    // epilogue: D[row][col]: col = lane&15, row = (lane>>4)*4 + r  (m89-verified)
    #pragma unroll
    for (int mt = 0; mt < 4; ++mt) {
        #pragma unroll
        for (int nt = 0; nt < 4; ++nt) {
            int col = bn + wc + nt * 16 + l15;
            if (col >= Nreal) continue;
            #pragma unroll
            for (int r = 0; r < 4; ++r) {
                int rw = bm + wr + mt * 16 + l4 * 4 + r;
                float v = acc[mt][nt][r];
                if (act == ACT_SOFTPLUS) {
                    v += bias[col];
                    v = fmaxf(v, 0.f) + log1pf(__expf(-fabsf(v)));
                }
                size_t ci = (size_t)rw * ldc + col;
                if (kSlices > 1) {
                    atomicAdd(&Cf[ci], v);
                } else if (hid) {
                    float m = msk[rw];
                    Cf[ci] = v * m + hid[ci] * (1.f - m);
                } else if (Cb) {
                    Cb[ci] = f2bf(v);
                } else {
                    Cf[ci] = v;
                }
            }
        }
    }
}

// ---------- depthwise conv (w=4) + silu; REV=anti-causal (reverse time) ----------
// x: stride 8192 (xz_cat half), u out: stride 2048.
template<int REV>
__global__ void conv_silu_kernel(const u16* __restrict__ x,
                                 const float* __restrict__ cw,
                                 const float* __restrict__ cb,
                                 u16* __restrict__ u)
{
    int d  = blockIdx.x * 256 + threadIdx.x;   // 0..2047
    int r0 = blockIdx.y * 16;                  // 16 | 2048
    float w0 = cw[d*4+0], w1 = cw[d*4+1], w2 = cw[d*4+2], w3 = cw[d*4+3];
    float bias = cb[d];
    if (!REV) {
        float x1, x2, x3;
        if (r0 & 2047) {
            x1 = bf2f(x[(size_t)(r0-1) * 8192 + d]);
            x2 = bf2f(x[(size_t)(r0-2) * 8192 + d]);
            x3 = bf2f(x[(size_t)(r0-3) * 8192 + d]);
        } else { x1 = x2 = x3 = 0.f; }
        #pragma unroll
        for (int i = 0; i < 16; ++i) {
            int r = r0 + i;
            float x0 = bf2f(x[(size_t)r * 8192 + d]);
            float acc = fmaf(w3, x0, fmaf(w2, x1, fmaf(w1, x2, fmaf(w0, x3, bias))));
            float sig = 1.f / (1.f + __expf(-acc));
            u[(size_t)r * 2048 + d] = f2bf(acc * sig);
            x3 = x2; x2 = x1; x1 = x0;
        }
    } else {
        // y[r] = b + w3*x[r] + w2*x[r+1] + w1*x[r+2] + w0*x[r+3], zero past batch end
        int le = (r0 + 15) & 2047;             // l of last row in block
        float x1, x2, x3;
        x1 = (le + 1 < 2048) ? bf2f(x[(size_t)(r0+16) * 8192 + d]) : 0.f;
        x2 = (le + 2 < 2048) ? bf2f(x[(size_t)(r0+17) * 8192 + d]) : 0.f;
        x3 = (le + 3 < 2048) ? bf2f(x[(size_t)(r0+18) * 8192 + d]) : 0.f;
        #pragma unroll
        for (int i = 15; i >= 0; --i) {
            int r = r0 + i;
            float x0 = bf2f(x[(size_t)r * 8192 + d]);
            float acc = fmaf(w3, x0, fmaf(w2, x1, fmaf(w1, x2, fmaf(w0, x3, bias))));
            float sig = 1.f / (1.f + __expf(-acc));
            u[(size_t)r * 2048 + d] = f2bf(acc * sig);
            x3 = x2; x2 = x1; x1 = x0;
        }
    }
}

// ---------- chunked selective scan, register-state layout; REV = reverse time ----------
#define NCH 32
#define CSZ 64
#define SUB 16
#define LW  264

template<int REV>
__global__ __launch_bounds__(256) void scan_part1(
    const u16* __restrict__ delta, const u16* __restrict__ u,
    const float* __restrict__ dbc, const float* __restrict__ A_log,
    float* __restrict__ P, float* __restrict__ S)
{
    __shared__ __align__(16) u16   dl_s[SUB * LW];
    __shared__ __align__(16) u16   ul_s[SUB * LW];
    __shared__ __align__(16) float b_s[SUB * 16];

    const int tid = threadIdx.x;
    const int d0  = blockIdx.x * 256;
    const int c   = blockIdx.y;
    const int b   = blockIdx.z;
    const int d   = d0 + tid;
    const size_t rbase = (size_t)b * 2048 + c * CSZ;

    float a2[16], h[16], p[16];
    #pragma unroll
    for (int q = 0; q < 4; ++q) {
        float4 al = *(const float4*)&A_log[(size_t)d * 16 + q * 4];
        a2[q*4+0] = -__expf(al.x) * 1.4426950408889634f;
        a2[q*4+1] = -__expf(al.y) * 1.4426950408889634f;
        a2[q*4+2] = -__expf(al.z) * 1.4426950408889634f;
        a2[q*4+3] = -__expf(al.w) * 1.4426950408889634f;
    }
    #pragma unroll
    for (int n = 0; n < 16; ++n) { h[n] = 0.f; p[n] = 1.f; }

    const int sr  = tid >> 4;
    const int sc16 = (tid & 15) * 16;

    for (int sch = 0; sch < CSZ / SUB; ++sch) {
        const int sch_ = REV ? (CSZ / SUB - 1 - sch) : sch;
        {
            size_t row = rbase + sch_ * SUB + sr;
            *(bf16x8*)&dl_s[sr * LW + sc16]     = *(const bf16x8*)&delta[row * 2048 + d0 + sc16];
            *(bf16x8*)&dl_s[sr * LW + sc16 + 8] = *(const bf16x8*)&delta[row * 2048 + d0 + sc16 + 8];
            *(bf16x8*)&ul_s[sr * LW + sc16]     = *(const bf16x8*)&u[row * 2048 + d0 + sc16];
            *(bf16x8*)&ul_s[sr * LW + sc16 + 8] = *(const bf16x8*)&u[row * 2048 + d0 + sc16 + 8];
            if (tid < 64) {
                int r2 = tid >> 2, c4 = (tid & 3) * 4;
                size_t g2 = rbase + sch_ * SUB + r2;
                *(float4*)&b_s[r2 * 16 + c4] = *(const float4*)&dbc[g2 * 96 + 64 + c4];
            }
        }
        __syncthreads();
        for (int s = 0; s < SUB; ++s) {
            const int s_ = REV ? (SUB - 1 - s) : s;
            float dv  = bf2f(dl_s[s_ * LW + tid]);
            float uv  = bf2f(ul_s[s_ * LW + tid]);
            float dvu = dv * uv;
            const float4* Bp = (const float4*)&b_s[s_ * 16];
            #pragma unroll
            for (int q = 0; q < 4; ++q) {
                float4 Bq = Bp[q];
                #pragma unroll
                for (int j = 0; j < 4; ++j) {
                    int n = q * 4 + j;
                    float dA = exp2f(dv * a2[n]);
                    h[n] = fmaf(dA, h[n], dvu * ((&Bq.x)[j]));
                    p[n] *= dA;
                }
            }
        }
        __syncthreads();
    }

    size_t base = (((size_t)(b * NCH + c)) << 15) + (size_t)d * 16;
    #pragma unroll
    for (int q = 0; q < 4; ++q) {
        float4 pv = { p[q*4+0], p[q*4+1], p[q*4+2], p[q*4+3] };
        float4 sv = { h[q*4+0], h[q*4+1], h[q*4+2], h[q*4+3] };
        *(float4*)&P[base + q * 4] = pv;
        *(float4*)&S[base + q * 4] = sv;
    }
}

template<int REV>
__global__ void scan_part2(const float* __restrict__ P, float* __restrict__ S)
{
    int i  = blockIdx.x * 256 + threadIdx.x;
    int b  = i >> 15;
    int dn = i & 32767;
    size_t base = ((size_t)b * NCH) << 15;
    float h = 0.f;
    #pragma unroll 4
    for (int cc = 0; cc < NCH; ++cc) {
        int c = REV ? (NCH - 1 - cc) : cc;
        size_t idx = base + ((size_t)c << 15) + dn;
        float p = P[idx];
        float s = S[idx];
        S[idx] = h;
        h = fmaf(p, h, s);
    }
}

template<int REV>
__global__ __launch_bounds__(256) void scan_part3(
    const u16* __restrict__ delta, const u16* __restrict__ u,
    const float* __restrict__ dbc, const u16* __restrict__ z,   // stride 8192
    const float* __restrict__ A_log, const float* __restrict__ Dp,
    const float* __restrict__ Hin, u16* __restrict__ y)          // stride 4096
{
    __shared__ __align__(16) u16   dl_s[SUB * LW];
    __shared__ __align__(16) u16   ul_s[SUB * LW];
    __shared__ __align__(16) u16   zl_s[SUB * LW];
    __shared__ __align__(16) float bc_s[SUB * 32];

    const int tid = threadIdx.x;
    const int d0  = blockIdx.x * 256;
    const int c   = blockIdx.y;
    const int b   = blockIdx.z;
    const int d   = d0 + tid;
    const size_t rbase = (size_t)b * 2048 + c * CSZ;

    float a2[16], h[16];
    #pragma unroll
    for (int q = 0; q < 4; ++q) {
        float4 al = *(const float4*)&A_log[(size_t)d * 16 + q * 4];
        a2[q*4+0] = -__expf(al.x) * 1.4426950408889634f;
        a2[q*4+1] = -__expf(al.y) * 1.4426950408889634f;
        a2[q*4+2] = -__expf(al.z) * 1.4426950408889634f;
        a2[q*4+3] = -__expf(al.w) * 1.4426950408889634f;
    }
    {
        size_t base = (((size_t)(b * NCH + c)) << 15) + (size_t)d * 16;
        #pragma unroll
        for (int q = 0; q < 4; ++q) {
            float4 hv = *(const float4*)&Hin[base + q * 4];
            h[q*4+0] = hv.x; h[q*4+1] = hv.y; h[q*4+2] = hv.z; h[q*4+3] = hv.w;
        }
    }
    const float Dd = Dp[d];

    const int sr   = tid >> 4;
    const int sc16 = (tid & 15) * 16;

    for (int sch = 0; sch < CSZ / SUB; ++sch) {
        const int sch_ = REV ? (CSZ / SUB - 1 - sch) : sch;
        {
            size_t row = rbase + sch_ * SUB + sr;
            *(bf16x8*)&dl_s[sr * LW + sc16]     = *(const bf16x8*)&delta[row * 2048 + d0 + sc16];
            *(bf16x8*)&dl_s[sr * LW + sc16 + 8] = *(const bf16x8*)&delta[row * 2048 + d0 + sc16 + 8];
            *(bf16x8*)&ul_s[sr * LW + sc16]     = *(const bf16x8*)&u[row * 2048 + d0 + sc16];
            *(bf16x8*)&ul_s[sr * LW + sc16 + 8] = *(const bf16x8*)&u[row * 2048 + d0 + sc16 + 8];
            *(bf16x8*)&zl_s[sr * LW + sc16]     = *(const bf16x8*)&z[row * 8192 + d0 + sc16];
            *(bf16x8*)&zl_s[sr * LW + sc16 + 8] = *(const bf16x8*)&z[row * 8192 + d0 + sc16 + 8];
            if (tid < 128) {
                int r2 = tid >> 3, c4 = (tid & 7) * 4;
                size_t g2 = rbase + sch_ * SUB + r2;
                *(float4*)&bc_s[r2 * 32 + c4] = *(const float4*)&dbc[g2 * 96 + 64 + c4];
            }
        }
        __syncthreads();
        for (int s = 0; s < SUB; ++s) {
            const int s_ = REV ? (SUB - 1 - s) : s;
            float dv  = bf2f(dl_s[s_ * LW + tid]);
            float uv  = bf2f(ul_s[s_ * LW + tid]);
            float dvu = dv * uv;
            float yv  = 0.f;
            const float4* Bp = (const float4*)&bc_s[s_ * 32];
            const float4* Cp = (const float4*)&bc_s[s_ * 32 + 16];
            #pragma unroll
            for (int q = 0; q < 4; ++q) {
                float4 Bq = Bp[q];
                float4 Cq = Cp[q];
                #pragma unroll
                for (int j = 0; j < 4; ++j) {
                    int n = q * 4 + j;
                    float dA = exp2f(dv * a2[n]);
                    h[n] = fmaf(dA, h[n], dvu * ((&Bq.x)[j]));
                    yv   = fmaf(h[n], ((&Cq.x)[j]), yv);
                }
            }
            float zv  = bf2f(zl_s[s_ * LW + tid]);
            float sig = 1.f / (1.f + __expf(-zv));
            float out = (yv + uv * Dd) * (zv * sig);
            y[(rbase + sch_ * SUB + s_) * 4096 + d] = f2bf(out);
        }
        __syncthreads();
    }
}

// ---------- elementwise ----------
__global__ void blend_kernel(const float* __restrict__ hidden, const float* __restrict__ mask,
                             const float* __restrict__ mw, const float* __restrict__ mb,
                             u16* __restrict__ xm)
{
    size_t i = (size_t)blockIdx.x * 256 + threadIdx.x;
    int r = (int)(i >> 10), c = (int)(i & 1023);
    float m = mask[r];
    float v = hidden[i] * m + (m * mw[c] + mb[c]) * (1.f - m);
    xm[i] = f2bf(v);
}

// ---------- fused weight conversion ----------
// dst0 = w_in_cat [8192][1024] (f rows then b rows)
// dst2 = w_out_cat [1024][4096] (per row: f K-half then b K-half)
// dst4/5 = w_dt f/b; dst6/7 = w_xp f/b padded 96->128 rows
struct CvtArgs { const float* src[8]; u16* dst[8]; };
__global__ void cvt_weights_kernel(CvtArgs a)
{
    size_t i = (size_t)blockIdx.x * 256 + threadIdx.x;   // < 13369344
    if (i < 8388608) {
        int s = (int)(i >> 22);
        size_t j = i & 4194303;
        a.dst[0][i] = f2bf(a.src[s][j]);                 // concat along rows
    } else if (i < 12582912) {
        size_t k = i - 8388608;
        int s = (int)(k >> 21);
        size_t j = k & 2097151;
        int n = (int)(j >> 11), kk = (int)(j & 2047);
        a.dst[2][(size_t)n * 4096 + s * 2048 + kk] = f2bf(a.src[2 + s][j]);  // K-interleave
    } else if (i < 12845056) {
        size_t k = i - 12582912;
        int s = 4 + (int)(k >> 17);
        size_t j = k & 131071;
        a.dst[s][j] = f2bf(a.src[s][j]);
    } else if (i < 13369344) {
        size_t k = i - 12845056;
        int s = 6 + (int)(k >> 18);
        size_t j = k & 262143;
        int r = (int)(j >> 11), c = (int)(j & 2047);
        a.dst[s][j] = (r < 96) ? f2bf(a.src[s][(size_t)r * 2048 + c]) : (u16)0;
    }
}

__global__ void cvt_dt_kernel(const float* __restrict__ dbc, u16* __restrict__ dst) {
    int i = blockIdx.x * 256 + threadIdx.x;   // 4096*64
    int r = i >> 6, c = i & 63;
    dst[i] = f2bf(dbc[(size_t)r * 96 + c]);
}

// ---------- launcher ----------
extern "C" void kernel_launch(void* const* d_in, const int* in_sizes, int n_in,
                              void* d_out, int out_size, void* d_ws, size_t ws_size,
                              hipStream_t stream)
{
    (void)in_sizes; (void)n_in; (void)out_size; (void)ws_size;
    const float* hidden = (const float*)d_in[0];
    const float* mask   = (const float*)d_in[1];
    const float* mpw    = (const float*)d_in[2];
    const float* mpb    = (const float*)d_in[3];

    char* ws = (char*)d_ws;
    size_t off = 0;
    auto alloc = [&](size_t bytes) -> char* {
        char* p = ws + off; off += (bytes + 255) & ~(size_t)255; return p;
    };
    u16*   xm     = (u16*)  alloc(4096ull * 1024 * 2);
    u16*   xz     = (u16*)  alloc(4096ull * 8192 * 2);   // both dirs, 64MB
    u16*   ub     = (u16*)  alloc(4096ull * 2048 * 2);   // per-dir reuse
    float* dbc    = (float*)alloc(4096ull * 96 * 4);
    u16*   dtb    = (u16*)  alloc(4096ull * 64 * 2);
    u16*   delta  = (u16*)  alloc(4096ull * 2048 * 2);
    u16*   yb     = (u16*)  alloc(4096ull * 4096 * 2);   // K-cat [y_f | y_b], 32MB
    float* Pbuf   = (float*)alloc(2ull * NCH * 2048 * 16 * 4);
    float* Sbuf   = (float*)alloc(2ull * NCH * 2048 * 16 * 4);
    u16*   w_in   = (u16*)  alloc(8192ull * 1024 * 2);   // row-cat
    u16*   w_out  = (u16*)  alloc(1024ull * 4096 * 2);   // K-cat
    u16*   w_xp[2] = { (u16*)alloc(128ull*2048*2), (u16*)alloc(128ull*2048*2) };
    u16*   w_dt[2] = { (u16*)alloc(2048ull*64*2),  (u16*)alloc(2048ull*64*2)  };

    {
        CvtArgs ca;
        ca.src[0] = (const float*)d_in[4];  ca.src[1] = (const float*)d_in[13];
        ca.src[2] = (const float*)d_in[12]; ca.src[3] = (const float*)d_in[21];
        ca.src[4] = (const float*)d_in[8];  ca.src[5] = (const float*)d_in[17];
        ca.src[6] = (const float*)d_in[7];  ca.src[7] = (const float*)d_in[16];
        ca.dst[0] = w_in;  ca.dst[1] = nullptr;
        ca.dst[2] = w_out; ca.dst[3] = nullptr;
        ca.dst[4] = w_dt[0]; ca.dst[5] = w_dt[1];
        ca.dst[6] = w_xp[0]; ca.dst[7] = w_xp[1];
        cvt_weights_kernel<<<(13369344 + 255) / 256, 256, 0, stream>>>(ca);
    }
    blend_kernel<<<16384, 256, 0, stream>>>(hidden, mask, mpw, mpb, xm);

    // fused dual-direction in_proj: xz[4096,8192] = xm @ [w_f; w_b]^T
    gemm_bt_kernel<<<dim3(64, 32, 1), 256, 0, stream>>>(
        xm, 1024, w_in, nullptr, xz, nullptr, 8192, 4096, 8192, 1024, 8192,
        ACT_NONE, 1, nullptr, nullptr);

    for (int dir = 0; dir < 2; ++dir) {
        int base = 4 + dir * 9;
        const float* conv_w = (const float*)d_in[base+1];
        const float* conv_b = (const float*)d_in[base+2];
        const float* dt_b   = (const float*)d_in[base+5];
        const float* A_log  = (const float*)d_in[base+6];
        const float* Dp     = (const float*)d_in[base+7];
        const u16* xi = xz + dir * 4096;          // stride 8192
        const u16* zp = xz + dir * 4096 + 2048;   // stride 8192

        if (dir == 0) conv_silu_kernel<0><<<dim3(8, 256), 256, 0, stream>>>(xi, conv_w, conv_b, ub);
        else          conv_silu_kernel<1><<<dim3(8, 256), 256, 0, stream>>>(xi, conv_w, conv_b, ub);

        hipMemsetAsync(dbc, 0, 4096ull * 96 * 4, stream);
        gemm_bt_kernel<<<dim3(1, 32, 4), 256, 0, stream>>>(
            ub, 2048, w_xp[dir], dbc, nullptr, nullptr, 96, 4096, 128, 2048, 96,
            ACT_NONE, 4, nullptr, nullptr);
        cvt_dt_kernel<<<(4096*64)/256, 256, 0, stream>>>(dbc, dtb);
        gemm_bt_kernel<<<dim3(16, 32, 1), 256, 0, stream>>>(
            dtb, 64, w_dt[dir], nullptr, delta, dt_b, 2048, 4096, 2048, 64, 2048,
            ACT_SOFTPLUS, 1, nullptr, nullptr);

        u16* yd = yb + dir * 2048;                // stride 4096
        if (dir == 0) {
            scan_part1<0><<<dim3(8, NCH, 2), 256, 0, stream>>>(delta, ub, dbc, A_log, Pbuf, Sbuf);
            scan_part2<0><<<256, 256, 0, stream>>>(Pbuf, Sbuf);
            scan_part3<0><<<dim3(8, NCH, 2), 256, 0, stream>>>(delta, ub, dbc, zp, A_log, Dp, Sbuf, yd);
        } else {
            scan_part1<1><<<dim3(8, NCH, 2), 256, 0, stream>>>(delta, ub, dbc, A_log, Pbuf, Sbuf);
            scan_part2<1><<<256, 256, 0, stream>>>(Pbuf, Sbuf);
            scan_part3<1><<<dim3(8, NCH, 2), 256, 0, stream>>>(delta, ub, dbc, zp, A_log, Dp, Sbuf, yd);
        }
    }

    // fused dual-direction out_proj (K-cat) + final mask blend
    gemm_bt_kernel<<<dim3(8, 32, 1), 256, 0, stream>>>(
        yb, 4096, w_out, (float*)d_out, nullptr, nullptr, 1024, 4096, 1024, 4096, 1024,
        ACT_NONE, 1, hidden, mask);
}

// Round 11
// 703.923 us; speedup vs baseline: 1.1595x; 1.0840x over previous
//
#include <hip/hip_runtime.h>
#include <hip/hip_bf16.h>
#include <stdint.h>

// ---------- types / helpers ----------
typedef unsigned short u16;
using bf16x8 = __attribute__((ext_vector_type(8))) short;
using f32x4  = __attribute__((ext_vector_type(4))) float;

#define AS1 __attribute__((address_space(1)))
#define AS3 __attribute__((address_space(3)))

__device__ __forceinline__ float bf2f(u16 x) {
    union { unsigned int u; float f; } v; v.u = ((unsigned int)x) << 16; return v.f;
}
__device__ __forceinline__ u16 f2bf(float f) {
    union { float f; unsigned int u; } v; v.f = f;
    return (u16)((v.u + 0x7fffu + ((v.u >> 16) & 1u)) >> 16);  // RNE
}

#define ACT_NONE 0
#define ACT_SOFTPLUS 1

// Per-direction overrides (used when gridDim.z spans both directions).
struct GemmSel {
    const u16* A1; const u16* B1;
    float* Cf1; u16* Cb1; const float* bias1;
};

// ---------- generic bf16 GEMM: C[M,N] = A[M,K] * B[N,K]^T ----------
// 128x128 tile, BK=64, 256 threads (4 waves 2x2), single-buffered LDS
// (round-7 proven; round-8 dbuf measured slower). blockIdx.z = dir*zDiv+slice.
// kSlices>1: split-K, fp32 atomicAdd into pre-zeroed Cf.
// hid!=null: fused final blend out = v*msk[row] + hid[ci]*(1-msk[row]).
__global__ __launch_bounds__(256) void gemm_bt_kernel(
    const u16* __restrict__ A, int lda,
    const u16* __restrict__ B,              // ldb == K
    float* __restrict__ Cf, u16* __restrict__ Cb,
    const float* __restrict__ bias,
    int ldc, int M, int N, int K, int Nreal,
    int act, int kSlices, int zDiv,
    const float* __restrict__ hid, const float* __restrict__ msk,
    GemmSel sel)
{
    __shared__ __align__(16) u16 As[128 * 64];
    __shared__ __align__(16) u16 Bs[128 * 64];

    const int tid  = threadIdx.x;
    const int bm   = blockIdx.y * 128;
    const int bn   = blockIdx.x * 128;
    const int lane = tid & 63;
    const int wid  = tid >> 6;
    const int wr   = (wid >> 1) * 64;
    const int wc   = (wid & 1) * 64;
    const int l15  = lane & 15;
    const int l4   = lane >> 4;

    const int dir   = blockIdx.z / zDiv;
    const int slice = blockIdx.z % zDiv;
    const u16* Ap = (dir && sel.A1) ? sel.A1 : A;
    const u16* Bp = (dir && sel.B1) ? sel.B1 : B;
    float* CfP = (dir && sel.Cf1) ? sel.Cf1 : Cf;
    u16*   CbP = (dir && sel.Cb1) ? sel.Cb1 : Cb;
    const float* biasP = (dir && sel.bias1) ? sel.bias1 : bias;

    const int kLen = K / kSlices;
    const int kt0  = (slice * kLen) >> 6;
    const int nK   = kLen >> 6;

    f32x4 acc[4][4];
    const f32x4 vzero = {0.f, 0.f, 0.f, 0.f};
    #pragma unroll
    for (int i = 0; i < 4; ++i)
        #pragma unroll
        for (int j = 0; j < 4; ++j) acc[i][j] = vzero;

    for (int t = 0; t < nK; ++t) {
        int kt = kt0 + t;
        #pragma unroll
        for (int i = 0; i < 4; ++i) {
            int off  = i * 4096 + tid * 16;
            int row  = off >> 7;
            int colB = off & 127;
            const char* src = (const char*)Ap + ((size_t)(bm + row) * lda + ((size_t)kt << 6)) * 2 + colB;
            __builtin_amdgcn_global_load_lds((const AS1 unsigned int*)src,
                                             (AS3 unsigned int*)((char*)As + off), 16, 0, 0);
        }
        #pragma unroll
        for (int i = 0; i < 4; ++i) {
            int off  = i * 4096 + tid * 16;
            int row  = off >> 7;
            int colB = off & 127;
            const char* src = (const char*)Bp + ((size_t)(bn + row) * K + ((size_t)kt << 6)) * 2 + colB;
            __builtin_amdgcn_global_load_lds((const AS1 unsigned int*)src,
                                             (AS3 unsigned int*)((char*)Bs + off), 16, 0, 0);
        }
        __syncthreads();

        #pragma unroll
        for (int kk = 0; kk < 2; ++kk) {
            bf16x8 af[4], bfr[4];
            #pragma unroll
            for (int mt = 0; mt < 4; ++mt) {
                int row = wr + mt * 16 + l15;
                af[mt] = *(const bf16x8*)((const char*)As + row * 128 + kk * 64 + l4 * 16);
            }
            #pragma unroll
            for (int nt = 0; nt < 4; ++nt) {
                int row = wc + nt * 16 + l15;
                bfr[nt] = *(const bf16x8*)((const char*)Bs + row * 128 + kk * 64 + l4 * 16);
            }
            #pragma unroll
            for (int mt = 0; mt < 4; ++mt)
                #pragma unroll
                for (int nt = 0; nt < 4; ++nt)
                    acc[mt][nt] = __builtin_amdgcn_mfma_f32_16x16x32_bf16(
                        af[mt], bfr[nt], acc[mt][nt], 0, 0, 0);
        }
        __syncthreads();
    }

    // epilogue: D[row][col]: col = lane&15, row = (lane>>4)*4 + r  (m89-verified)
    #pragma unroll
    for (int mt = 0; mt < 4; ++mt) {
        #pragma unroll
        for (int nt = 0; nt < 4; ++nt) {
            int col = bn + wc + nt * 16 + l15;
            if (col >= Nreal) continue;
            #pragma unroll
            for (int r = 0; r < 4; ++r) {
                int rw = bm + wr + mt * 16 + l4 * 4 + r;
                float v = acc[mt][nt][r];
                if (act == ACT_SOFTPLUS) {
                    v += biasP[col];
                    v = fmaxf(v, 0.f) + log1pf(__expf(-fabsf(v)));
                }
                size_t ci = (size_t)rw * ldc + col;
                if (kSlices > 1) {
                    atomicAdd(&CfP[ci], v);
                } else if (hid) {
                    float m = msk[rw];
                    CfP[ci] = v * m + hid[ci] * (1.f - m);
                } else if (CbP) {
                    CbP[ci] = f2bf(v);
                } else {
                    CfP[ci] = v;
                }
            }
        }
    }
}

// ---------- dual-direction depthwise conv (w=4) + silu ----------
// blockIdx.z = dir. dir0 causal, dir1 anti-causal (reverse time).
struct ConvArgs { const float* cw[2]; const float* cb[2]; u16* u[2]; };
__global__ void conv_silu_dual(const u16* __restrict__ xz, ConvArgs a)
{
    const int dir = blockIdx.z;
    const u16* x = xz + dir * 4096;            // stride 8192
    const float* cw = a.cw[dir];
    const float* cb = a.cb[dir];
    u16* u = a.u[dir];

    int d  = blockIdx.x * 256 + threadIdx.x;   // 0..2047
    int r0 = blockIdx.y * 16;
    float w0 = cw[d*4+0], w1 = cw[d*4+1], w2 = cw[d*4+2], w3 = cw[d*4+3];
    float bias = cb[d];
    if (dir == 0) {
        float x1, x2, x3;
        if (r0 & 2047) {
            x1 = bf2f(x[(size_t)(r0-1) * 8192 + d]);
            x2 = bf2f(x[(size_t)(r0-2) * 8192 + d]);
            x3 = bf2f(x[(size_t)(r0-3) * 8192 + d]);
        } else { x1 = x2 = x3 = 0.f; }
        #pragma unroll
        for (int i = 0; i < 16; ++i) {
            int r = r0 + i;
            float x0 = bf2f(x[(size_t)r * 8192 + d]);
            float acc = fmaf(w3, x0, fmaf(w2, x1, fmaf(w1, x2, fmaf(w0, x3, bias))));
            float sig = 1.f / (1.f + __expf(-acc));
            u[(size_t)r * 2048 + d] = f2bf(acc * sig);
            x3 = x2; x2 = x1; x1 = x0;
        }
    } else {
        int le = (r0 + 15) & 2047;
        float x1, x2, x3;
        x1 = (le + 1 < 2048) ? bf2f(x[(size_t)(r0+16) * 8192 + d]) : 0.f;
        x2 = (le + 2 < 2048) ? bf2f(x[(size_t)(r0+17) * 8192 + d]) : 0.f;
        x3 = (le + 3 < 2048) ? bf2f(x[(size_t)(r0+18) * 8192 + d]) : 0.f;
        #pragma unroll
        for (int i = 15; i >= 0; --i) {
            int r = r0 + i;
            float x0 = bf2f(x[(size_t)r * 8192 + d]);
            float acc = fmaf(w3, x0, fmaf(w2, x1, fmaf(w1, x2, fmaf(w0, x3, bias))));
            float sig = 1.f / (1.f + __expf(-acc));
            u[(size_t)r * 2048 + d] = f2bf(acc * sig);
            x3 = x2; x2 = x1; x1 = x0;
        }
    }
}

// ---------- chunked selective scan, dual-direction ----------
// delta lives in xz xi columns (stride 8192). blockIdx.z = b + 2*dir.
#define NCH 32
#define CSZ 64
#define SUB 16
#define LW  264

struct ScanArgs {
    const u16* delta[2];   // stride 8192
    const u16* u[2];       // stride 2048
    const float* dbc[2];   // stride 96
    const u16* z[2];       // stride 8192
    const float* Alog[2];
    const float* Dp[2];
    float* P[2]; float* S[2];
    u16* y[2];             // stride 4096
};

__global__ __launch_bounds__(256) void scan_part1_dual(ScanArgs sa)
{
    __shared__ __align__(16) u16   dl_s[SUB * LW];
    __shared__ __align__(16) u16   ul_s[SUB * LW];
    __shared__ __align__(16) float b_s[SUB * 16];

    const int tid = threadIdx.x;
    const int d0  = blockIdx.x * 256;
    const int c   = blockIdx.y;
    const int dir = blockIdx.z >> 1;
    const int b   = blockIdx.z & 1;
    const int rev = dir;
    const int d   = d0 + tid;
    const size_t rbase = (size_t)b * 2048 + c * CSZ;

    const u16* D = sa.delta[dir];
    const u16* U = sa.u[dir];
    const float* BC = sa.dbc[dir];

    float a2[16], h[16], p[16];
    #pragma unroll
    for (int q = 0; q < 4; ++q) {
        float4 al = *(const float4*)&sa.Alog[dir][(size_t)d * 16 + q * 4];
        a2[q*4+0] = -__expf(al.x) * 1.4426950408889634f;
        a2[q*4+1] = -__expf(al.y) * 1.4426950408889634f;
        a2[q*4+2] = -__expf(al.z) * 1.4426950408889634f;
        a2[q*4+3] = -__expf(al.w) * 1.4426950408889634f;
    }
    #pragma unroll
    for (int n = 0; n < 16; ++n) { h[n] = 0.f; p[n] = 1.f; }

    const int sr  = tid >> 4;
    const int sc16 = (tid & 15) * 16;

    for (int sch = 0; sch < CSZ / SUB; ++sch) {
        const int sch_ = rev ? (CSZ / SUB - 1 - sch) : sch;
        {
            size_t row = rbase + sch_ * SUB + sr;
            *(bf16x8*)&dl_s[sr * LW + sc16]     = *(const bf16x8*)&D[row * 8192 + d0 + sc16];
            *(bf16x8*)&dl_s[sr * LW + sc16 + 8] = *(const bf16x8*)&D[row * 8192 + d0 + sc16 + 8];
            *(bf16x8*)&ul_s[sr * LW + sc16]     = *(const bf16x8*)&U[row * 2048 + d0 + sc16];
            *(bf16x8*)&ul_s[sr * LW + sc16 + 8] = *(const bf16x8*)&U[row * 2048 + d0 + sc16 + 8];
            if (tid < 64) {
                int r2 = tid >> 2, c4 = (tid & 3) * 4;
                size_t g2 = rbase + sch_ * SUB + r2;
                *(float4*)&b_s[r2 * 16 + c4] = *(const float4*)&BC[g2 * 96 + 64 + c4];
            }
        }
        __syncthreads();
        for (int s = 0; s < SUB; ++s) {
            const int s_ = rev ? (SUB - 1 - s) : s;
            float dv  = bf2f(dl_s[s_ * LW + tid]);
            float uv  = bf2f(ul_s[s_ * LW + tid]);
            float dvu = dv * uv;
            const float4* Bp = (const float4*)&b_s[s_ * 16];
            #pragma unroll
            for (int q = 0; q < 4; ++q) {
                float4 Bq = Bp[q];
                #pragma unroll
                for (int j = 0; j < 4; ++j) {
                    int n = q * 4 + j;
                    float dA = exp2f(dv * a2[n]);
                    h[n] = fmaf(dA, h[n], dvu * ((&Bq.x)[j]));
                    p[n] *= dA;
                }
            }
        }
        __syncthreads();
    }

    size_t base = (((size_t)(b * NCH + c)) << 15) + (size_t)d * 16;
    #pragma unroll
    for (int q = 0; q < 4; ++q) {
        float4 pv = { p[q*4+0], p[q*4+1], p[q*4+2], p[q*4+3] };
        float4 sv = { h[q*4+0], h[q*4+1], h[q*4+2], h[q*4+3] };
        *(float4*)&sa.P[dir][base + q * 4] = pv;
        *(float4*)&sa.S[dir][base + q * 4] = sv;
    }
}

__global__ void scan_part2_dual(ScanArgs sa)
{
    int i   = blockIdx.x * 256 + threadIdx.x;   // < 131072
    int dir = i >> 16;
    int k   = i & 65535;
    int b   = k >> 15;
    int dn  = k & 32767;
    const float* P = sa.P[dir];
    float* S = sa.S[dir];
    size_t base = ((size_t)b * NCH) << 15;
    float h = 0.f;
    #pragma unroll 4
    for (int cc = 0; cc < NCH; ++cc) {
        int c = dir ? (NCH - 1 - cc) : cc;
        size_t idx = base + ((size_t)c << 15) + dn;
        float p = P[idx];
        float s = S[idx];
        S[idx] = h;
        h = fmaf(p, h, s);
    }
}

__global__ __launch_bounds__(256) void scan_part3_dual(ScanArgs sa)
{
    __shared__ __align__(16) u16   dl_s[SUB * LW];
    __shared__ __align__(16) u16   ul_s[SUB * LW];
    __shared__ __align__(16) u16   zl_s[SUB * LW];
    __shared__ __align__(16) float bc_s[SUB * 32];

    const int tid = threadIdx.x;
    const int d0  = blockIdx.x * 256;
    const int c   = blockIdx.y;
    const int dir = blockIdx.z >> 1;
    const int b   = blockIdx.z & 1;
    const int rev = dir;
    const int d   = d0 + tid;
    const size_t rbase = (size_t)b * 2048 + c * CSZ;

    const u16* D = sa.delta[dir];
    const u16* U = sa.u[dir];
    const float* BC = sa.dbc[dir];
    const u16* Z = sa.z[dir];
    u16* Y = sa.y[dir];

    float a2[16], h[16];
    #pragma unroll
    for (int q = 0; q < 4; ++q) {
        float4 al = *(const float4*)&sa.Alog[dir][(size_t)d * 16 + q * 4];
        a2[q*4+0] = -__expf(al.x) * 1.4426950408889634f;
        a2[q*4+1] = -__expf(al.y) * 1.4426950408889634f;
        a2[q*4+2] = -__expf(al.z) * 1.4426950408889634f;
        a2[q*4+3] = -__expf(al.w) * 1.4426950408889634f;
    }
    {
        size_t base = (((size_t)(b * NCH + c)) << 15) + (size_t)d * 16;
        #pragma unroll
        for (int q = 0; q < 4; ++q) {
            float4 hv = *(const float4*)&sa.S[dir][base + q * 4];
            h[q*4+0] = hv.x; h[q*4+1] = hv.y; h[q*4+2] = hv.z; h[q*4+3] = hv.w;
        }
    }
    const float Dd = sa.Dp[dir][d];

    const int sr   = tid >> 4;
    const int sc16 = (tid & 15) * 16;

    for (int sch = 0; sch < CSZ / SUB; ++sch) {
        const int sch_ = rev ? (CSZ / SUB - 1 - sch) : sch;
        {
            size_t row = rbase + sch_ * SUB + sr;
            *(bf16x8*)&dl_s[sr * LW + sc16]     = *(const bf16x8*)&D[row * 8192 + d0 + sc16];
            *(bf16x8*)&dl_s[sr * LW + sc16 + 8] = *(const bf16x8*)&D[row * 8192 + d0 + sc16 + 8];
            *(bf16x8*)&ul_s[sr * LW + sc16]     = *(const bf16x8*)&U[row * 2048 + d0 + sc16];
            *(bf16x8*)&ul_s[sr * LW + sc16 + 8] = *(const bf16x8*)&U[row * 2048 + d0 + sc16 + 8];
            *(bf16x8*)&zl_s[sr * LW + sc16]     = *(const bf16x8*)&Z[row * 8192 + d0 + sc16];
            *(bf16x8*)&zl_s[sr * LW + sc16 + 8] = *(const bf16x8*)&Z[row * 8192 + d0 + sc16 + 8];
            if (tid < 128) {
                int r2 = tid >> 3, c4 = (tid & 7) * 4;
                size_t g2 = rbase + sch_ * SUB + r2;
                *(float4*)&bc_s[r2 * 32 + c4] = *(const float4*)&BC[g2 * 96 + 64 + c4];
            }
        }
        __syncthreads();
        for (int s = 0; s < SUB; ++s) {
            const int s_ = rev ? (SUB - 1 - s) : s;
            float dv  = bf2f(dl_s[s_ * LW + tid]);
            float uv  = bf2f(ul_s[s_ * LW + tid]);
            float dvu = dv * uv;
            float yv  = 0.f;
            const float4* Bp = (const float4*)&bc_s[s_ * 32];
            const float4* Cp = (const float4*)&bc_s[s_ * 32 + 16];
            #pragma unroll
            for (int q = 0; q < 4; ++q) {
                float4 Bq = Bp[q];
                float4 Cq = Cp[q];
                #pragma unroll
                for (int j = 0; j < 4; ++j) {
                    int n = q * 4 + j;
                    float dA = exp2f(dv * a2[n]);
                    h[n] = fmaf(dA, h[n], dvu * ((&Bq.x)[j]));
                    yv   = fmaf(h[n], ((&Cq.x)[j]), yv);
                }
            }
            float zv  = bf2f(zl_s[s_ * LW + tid]);
            float sig = 1.f / (1.f + __expf(-zv));
            float out = (yv + uv * Dd) * (zv * sig);
            Y[(rbase + sch_ * SUB + s_) * 4096 + d] = f2bf(out);
        }
        __syncthreads();
    }
}

// ---------- fused prep: weight conversion + input blend ----------
// seg0: w_in row-cat [8192][1024]; seg1: w_out K-cat [1024][4096];
// seg2: w_dt f/b; seg3: w_xp f/b padded; seg4: xm blend.
struct PrepArgs {
    const float* src_in[2]; const float* src_out[2];
    const float* src_dt[2]; const float* src_xp[2];
    u16* w_in; u16* w_out; u16* w_dt[2]; u16* w_xp[2];
    const float* hidden; const float* mask; const float* mw; const float* mb;
    u16* xm;
};
__global__ void prep_kernel(PrepArgs a)
{
    size_t i = (size_t)blockIdx.x * 256 + threadIdx.x;   // < 17563648
    if (i < 8388608) {
        int s = (int)(i >> 22);
        size_t j = i & 4194303;
        a.w_in[i] = f2bf(a.src_in[s][j]);
    } else if (i < 12582912) {
        size_t k = i - 8388608;
        int s = (int)(k >> 21);
        size_t j = k & 2097151;
        int n = (int)(j >> 11), kk = (int)(j & 2047);
        a.w_out[(size_t)n * 4096 + s * 2048 + kk] = f2bf(a.src_out[s][j]);
    } else if (i < 12845056) {
        size_t k = i - 12582912;
        int s = (int)(k >> 17);
        size_t j = k & 131071;
        a.w_dt[s][j] = f2bf(a.src_dt[s][j]);
    } else if (i < 13369344) {
        size_t k = i - 12845056;
        int s = (int)(k >> 18);
        size_t j = k & 262143;
        int r = (int)(j >> 11), c = (int)(j & 2047);
        a.w_xp[s][j] = (r < 96) ? f2bf(a.src_xp[s][(size_t)r * 2048 + c]) : (u16)0;
    } else if (i < 17563648) {
        size_t k = i - 13369344;           // < 4194304
        int r = (int)(k >> 10), c = (int)(k & 1023);
        float m = a.mask[r];
        float v = a.hidden[k] * m + (m * a.mw[c] + a.mb[c]) * (1.f - m);
        a.xm[k] = f2bf(v);
    }
}

__global__ void cvt_dt_dual(const float* __restrict__ dbc, u16* __restrict__ dtb)
{
    int i = blockIdx.x * 256 + threadIdx.x;   // < 524288
    int dir = i >> 18;
    int j = i & 262143;
    int r = j >> 6, c = j & 63;
    dtb[i] = f2bf(dbc[(size_t)dir * 4096 * 96 + (size_t)r * 96 + c]);
}

// ---------- launcher ----------
extern "C" void kernel_launch(void* const* d_in, const int* in_sizes, int n_in,
                              void* d_out, int out_size, void* d_ws, size_t ws_size,
                              hipStream_t stream)
{
    (void)in_sizes; (void)n_in; (void)out_size; (void)ws_size;
    const float* hidden = (const float*)d_in[0];
    const float* mask   = (const float*)d_in[1];

    char* ws = (char*)d_ws;
    size_t off = 0;
    auto alloc = [&](size_t bytes) -> char* {
        char* p = ws + off; off += (bytes + 255) & ~(size_t)255; return p;
    };
    u16*   xm    = (u16*)  alloc(4096ull * 1024 * 2);
    u16*   xz    = (u16*)  alloc(4096ull * 8192 * 2);    // xi (→delta after conv) + z, both dirs
    u16*   ub0   = (u16*)  alloc(4096ull * 2048 * 2);
    u16*   ub1   = (u16*)  alloc(4096ull * 2048 * 2);
    float* dbc   = (float*)alloc(2ull * 4096 * 96 * 4);  // both dirs contiguous
    u16*   dtb   = (u16*)  alloc(2ull * 4096 * 64 * 2);
    u16*   yb    = (u16*)  alloc(4096ull * 4096 * 2);    // K-cat [y_f | y_b]
    float* Pbuf  = (float*)alloc(2ull * 2 * NCH * 2048 * 16 * 4);
    float* Sbuf  = (float*)alloc(2ull * 2 * NCH * 2048 * 16 * 4);
    u16*   w_in  = (u16*)  alloc(8192ull * 1024 * 2);
    u16*   w_out = (u16*)  alloc(1024ull * 4096 * 2);
    u16*   w_xp0 = (u16*)  alloc(128ull * 2048 * 2);
    u16*   w_xp1 = (u16*)  alloc(128ull * 2048 * 2);
    u16*   w_dt0 = (u16*)  alloc(2048ull * 64 * 2);
    u16*   w_dt1 = (u16*)  alloc(2048ull * 64 * 2);

    const size_t PS_DIR = 2ull * NCH * 2048 * 16;        // floats per dir

    // 1. prep: all weight conversions + input blend
    {
        PrepArgs pa;
        pa.src_in[0]  = (const float*)d_in[4];  pa.src_in[1]  = (const float*)d_in[13];
        pa.src_out[0] = (const float*)d_in[12]; pa.src_out[1] = (const float*)d_in[21];
        pa.src_dt[0]  = (const float*)d_in[8];  pa.src_dt[1]  = (const float*)d_in[17];
        pa.src_xp[0]  = (const float*)d_in[7];  pa.src_xp[1]  = (const float*)d_in[16];
        pa.w_in = w_in; pa.w_out = w_out;
        pa.w_dt[0] = w_dt0; pa.w_dt[1] = w_dt1;
        pa.w_xp[0] = w_xp0; pa.w_xp[1] = w_xp1;
        pa.hidden = hidden; pa.mask = mask;
        pa.mw = (const float*)d_in[2]; pa.mb = (const float*)d_in[3];
        pa.xm = xm;
        prep_kernel<<<(17563648 + 255) / 256, 256, 0, stream>>>(pa);
    }

    GemmSel nosel = {nullptr, nullptr, nullptr, nullptr, nullptr};

    // 2. fused dual-direction in_proj: xz[4096,8192] = xm @ [w_f; w_b]^T
    gemm_bt_kernel<<<dim3(64, 32, 1), 256, 0, stream>>>(
        xm, 1024, w_in, nullptr, xz, nullptr, 8192, 4096, 8192, 1024, 8192,
        ACT_NONE, 1, 1, nullptr, nullptr, nosel);

    // 3. conv+silu both dirs
    {
        ConvArgs ca;
        ca.cw[0] = (const float*)d_in[5];  ca.cw[1] = (const float*)d_in[14];
        ca.cb[0] = (const float*)d_in[6];  ca.cb[1] = (const float*)d_in[15];
        ca.u[0] = ub0; ca.u[1] = ub1;
        conv_silu_dual<<<dim3(8, 256, 2), 256, 0, stream>>>(xz, ca);
    }

    // 4-5. xproj both dirs, split-K x4, atomic into zeroed dbc
    hipMemsetAsync(dbc, 0, 2ull * 4096 * 96 * 4, stream);
    {
        GemmSel sel = {ub1, w_xp1, dbc + 4096 * 96, nullptr, nullptr};
        gemm_bt_kernel<<<dim3(1, 32, 8), 256, 0, stream>>>(
            ub0, 2048, w_xp0, dbc, nullptr, nullptr, 96, 4096, 128, 2048, 96,
            ACT_NONE, 4, 4, nullptr, nullptr, sel);
    }

    // 6. dt slice -> bf16, both dirs
    cvt_dt_dual<<<524288 / 256, 256, 0, stream>>>(dbc, dtb);

    // 7. dt_proj + softplus both dirs; delta written into xz xi columns (ldc=8192)
    {
        GemmSel sel = {dtb + 262144, w_dt1, nullptr, xz + 4096, (const float*)d_in[18]};
        gemm_bt_kernel<<<dim3(16, 32, 2), 256, 0, stream>>>(
            dtb, 64, w_dt0, nullptr, xz, (const float*)d_in[9], 8192, 4096, 2048, 64, 2048,
            ACT_SOFTPLUS, 1, 1, nullptr, nullptr, sel);
    }

    // 8-10. scans both dirs
    {
        ScanArgs sa;
        sa.delta[0] = xz;            sa.delta[1] = xz + 4096;
        sa.u[0] = ub0;               sa.u[1] = ub1;
        sa.dbc[0] = dbc;             sa.dbc[1] = dbc + 4096 * 96;
        sa.z[0] = xz + 2048;         sa.z[1] = xz + 4096 + 2048;
        sa.Alog[0] = (const float*)d_in[10]; sa.Alog[1] = (const float*)d_in[19];
        sa.Dp[0]   = (const float*)d_in[11]; sa.Dp[1]   = (const float*)d_in[20];
        sa.P[0] = Pbuf;              sa.P[1] = Pbuf + PS_DIR;
        sa.S[0] = Sbuf;              sa.S[1] = Sbuf + PS_DIR;
        sa.y[0] = yb;                sa.y[1] = yb + 2048;
        scan_part1_dual<<<dim3(8, NCH, 4), 256, 0, stream>>>(sa);
        scan_part2_dual<<<512, 256, 0, stream>>>(sa);
        scan_part3_dual<<<dim3(8, NCH, 4), 256, 0, stream>>>(sa);
    }

    // 11. fused dual-direction out_proj (K-cat) + final mask blend
    gemm_bt_kernel<<<dim3(8, 32, 1), 256, 0, stream>>>(
        yb, 4096, w_out, (float*)d_out, nullptr, nullptr, 1024, 4096, 1024, 4096, 1024,
        ACT_NONE, 1, 1, hidden, mask, nosel);
}